// Round 10
// baseline (164.955 us; speedup 1.0000x reference)
//
#include <hip/hip_runtime.h>
#include <hip/hip_bf16.h>
#include <math.h>

#define MARGIN_C 0.3f
#define CLST_SCALE 0.8f
#define SEP_SCALE 0.08f
#define DIV_SCALE 0.01f
#define CONTRASTIVE_SCALE 0.1f

#define INFF __builtin_huge_valf()
#define NVEC 64

// ---------------- K_A: per-sample min-distance, wave-per-sample ------------
// Measured R8 probe: F ~= 15-16.5 us (~4 TB/s effective on the 65.5 MB read).
extern __shared__ float fk_lds[];
__global__ __launch_bounds__(1024) void front_kernel(
    const float* __restrict__ sims, const int* __restrict__ labels,
    const int* __restrict__ pidx,
    float* __restrict__ own_arr, float* __restrict__ sep_arr,
    float* __restrict__ cls3, float* __restrict__ svec,
    double* __restrict__ diag, unsigned* __restrict__ done,
    int B, int C, int D, int P, int strideF) {
    int t = threadIdx.x;
    int nthr = blockDim.x;
    int wave = t >> 6, lane = t & 63;
    int bid = blockIdx.x;
    if (bid == 0) {
        for (int i = t; i < 3 * C; i += nthr) cls3[i] = 0.0f;
        for (int i = t; i < D; i += nthr) svec[i] = 0.0f;
        if (t == 0) { *diag = 0.0; *done = 0u; }
    }
    int rowlen = C * P;
    int rows = nthr >> 6;
    int b = bid * rows + wave;
    float* row = fk_lds + wave * strideF;
    if (b < B) {
        const float* src = sims + (size_t)b * rowlen;
        if ((rowlen & 3) == 0) {
            int nf4 = rowlen >> 2;
            const float4* s4 = reinterpret_cast<const float4*>(src);
            for (int q = lane; q < nf4; q += 64)
                *reinterpret_cast<float4*>(row + 4 * q) = s4[q];
        } else {
            for (int q = lane; q < rowlen; q += 64) row[q] = src[q];
        }
    }
    __syncthreads();
    if (b >= B) return;
    int label = labels[b];
    float own = INFF, other = INFF;
    for (int cc = 0; cc < C; cc += 64) {
        int c = cc + lane;
        if (c < C) {
            int cnt = pidx[2 * c + 1] - pidx[2 * c];
            const float* cb = row + c * P;
            float m = INFF;
            if ((P & 1) == 0) {
                for (int p = 0; p < P; p += 2) {
                    float2 v = *reinterpret_cast<const float2*>(cb + p);
                    float d0 = (p < cnt) ? (1.0f - v.x) : INFF;
                    float d1 = (p + 1 < cnt) ? (1.0f - v.y) : INFF;
                    m = fminf(m, fminf(d0, d1));
                }
            } else {
                for (int p = 0; p < P; ++p) {
                    float v = cb[p];
                    m = fminf(m, (p < cnt) ? (1.0f - v) : INFF);
                }
            }
            if (c == label) own = m;
            else other = fminf(other, m);
        }
    }
#pragma unroll
    for (int off = 32; off > 0; off >>= 1) {
        own = fminf(own, __shfl_xor(own, off));
        other = fminf(other, __shfl_xor(other, off));
    }
    if (lane == 0) {
        own_arr[b] = own;
        sep_arr[b] = fmaxf(MARGIN_C - other, 0.0f);
    }
}

// ---------------- K_B: {seg-histogram | class-Gram | vecsum} + finalize ----
// TIMING PROBE this round: launched 3x. Stream-ordered launches mean the
// done-counter reaches nbTot exactly at the end of launch 1 -> finalize
// fires once with correct values; later launches' extra accumulation is
// never re-read. Delta(total) vs R7 = 2R + 2*gap.
extern __shared__ float rk_lds[];
__global__ __launch_bounds__(256) void reduce_kernel(
    const int* __restrict__ labels, const float* __restrict__ own_arr,
    const float* __restrict__ sep_arr, const int* __restrict__ pidx,
    const int* __restrict__ vmask, const float* __restrict__ protos,
    float* __restrict__ cls3, float* __restrict__ cls_pair,
    float* __restrict__ svec, double* __restrict__ diag,
    unsigned* __restrict__ done, float* __restrict__ out,
    int B, int C, int T, int D, int P, int nSeg, int rpb, int chunk,
    unsigned nbTot) {
    __shared__ float wsum[4];
    __shared__ double rd[4];
    __shared__ float invn[128];
    __shared__ int vmf[128];
    __shared__ unsigned lastf;
    int t = threadIdx.x, bid = blockIdx.x;
    int wv = t >> 6, lane = t & 63;

    if (bid < nSeg) {
        for (int i = t; i < 3 * C; i += 256) rk_lds[i] = 0.0f;
        __syncthreads();
        int i = bid * 256 + t;
        if (i < B) {
            int lb = labels[i];
            atomicAdd(&rk_lds[lb], own_arr[i]);
            atomicAdd(&rk_lds[C + lb], 1.0f);
            atomicAdd(&rk_lds[2 * C + lb], sep_arr[i]);
        }
        __syncthreads();
        for (int i2 = t; i2 < 3 * C; i2 += 256) {
            float v = rk_lds[i2];
            if (v != 0.0f) unsafeAtomicAdd(&cls3[i2], v);
        }
    } else if (bid < nSeg + C) {
        int c = bid - nSeg;
        int s0 = pidx[2 * c], e = pidx[2 * c + 1];
        int n = e - s0;
        if (n > P) n = P;
        if (n > 128) n = 128;
        if (n < 0) n = 0;
        for (int idx = t; idx < n * D; idx += 256)
            rk_lds[idx] = protos[(size_t)s0 * D + idx];
        __syncthreads();
        for (int i = wv; i < n; i += 4) {
            float ss = 0.0f;
            for (int q = lane; q < D; q += 64) { float v = rk_lds[i * D + q]; ss += v * v; }
#pragma unroll
            for (int off = 32; off > 0; off >>= 1) ss += __shfl_xor(ss, off);
            if (lane == 0) invn[i] = 1.0f / fmaxf(sqrtf(ss), 1e-12f);
        }
        __syncthreads();
        int npair = n * (n - 1) / 2;
        float tot = 0.0f;
        for (int l = wv; l < npair; l += 4) {
            int i = 0, rem = l;
            while (rem >= n - 1 - i) { rem -= n - 1 - i; ++i; }
            int j = i + 1 + rem;
            float acc = 0.0f;
            if ((D & 3) == 0) {
                for (int q = lane * 4; q < D; q += 256) {
                    float4 a = *reinterpret_cast<const float4*>(&rk_lds[i * D + q]);
                    float4 b = *reinterpret_cast<const float4*>(&rk_lds[j * D + q]);
                    acc += a.x * b.x + a.y * b.y + a.z * b.z + a.w * b.w;
                }
            } else {
                for (int q = lane; q < D; q += 64) acc += rk_lds[i * D + q] * rk_lds[j * D + q];
            }
#pragma unroll
            for (int off = 32; off > 0; off >>= 1) acc += __shfl_xor(acc, off);
            tot += 2.0f * fmaxf(acc * invn[i] * invn[j] - 0.5f, 0.0f);
        }
        if (lane == 0) wsum[wv] = tot;
        __syncthreads();
        if (t == 0) cls_pair[c] = wsum[0] + wsum[1] + wsum[2] + wsum[3];
    } else {
        int vb = bid - nSeg - C;
        int r0 = vb * rpb, r1 = r0 + rpb;
        if (r1 > T) r1 = T;
        double sqd = 0.0;
        for (int base = r0; base < r1; base += chunk) {
            int nr = r1 - base;
            if (nr > chunk) nr = chunk;
            for (int idx = t; idx < nr * D; idx += 256)
                rk_lds[idx] = protos[(size_t)base * D + idx];
            __syncthreads();
            for (int r = wv; r < nr; r += 4) {
                float ss = 0.0f;
                for (int q = lane; q < D; q += 64) { float v = rk_lds[r * D + q]; ss += v * v; }
#pragma unroll
                for (int off = 32; off > 0; off >>= 1) ss += __shfl_xor(ss, off);
                if (lane == 0) {
                    invn[r] = 1.0f / fmaxf(sqrtf(ss), 1e-12f);
                    vmf[r] = vmask[base + r];
                }
            }
            __syncthreads();
            for (int d = t; d < D; d += 256) {
                float sv = 0.0f, sq = 0.0f;
                for (int r = 0; r < nr; ++r) {
                    if (vmf[r] != 0) {
                        float v = rk_lds[r * D + d] * invn[r];
                        sv += v;
                        sq += v * v;
                    }
                }
                if (sv != 0.0f) unsafeAtomicAdd(&svec[d], sv);
                sqd += (double)sq;
            }
            __syncthreads();
        }
#pragma unroll
        for (int off = 32; off > 0; off >>= 1) sqd += __shfl_xor(sqd, off);
        if ((t & 63) == 0) rd[t >> 6] = sqd;
        __syncthreads();
        if (t == 0) {
            double s = rd[0] + rd[1] + rd[2] + rd[3];
            if (s != 0.0) unsafeAtomicAdd(diag, s);
        }
    }

    __threadfence();
    if (t == 0) lastf = (atomicAdd(done, 1u) == nbTot - 1u) ? 1u : 0u;
    __syncthreads();
    if (!lastf || t >= 64) return;
    __threadfence();
    int lane2 = t;
    float cl = 0.0f, sp = 0.0f, dv = 0.0f;
    int nval = 0, ndv = 0, V = 0;
    const float* cls_sum = cls3;
    const float* cls_n = cls3 + C;
    const float* sep_sum = cls3 + 2 * C;
    for (int c = lane2; c < C; c += 64) {
        float n = cls_n[c];
        if (n > 0.0f) {
            nval += 1;
            float nm = fmaxf(n, 1.0f);
            float w = 1.0f / sqrtf(n + 1e-6f);
            cl += w * (cls_sum[c] / nm);
            sp += sep_sum[c] / nm;
        }
        int cnt = pidx[2 * c + 1] - pidx[2 * c];
        if (cnt > 1) {
            ndv += 1;
            float np = (float)(cnt * (cnt - 1));
            dv += cls_pair[c] / fmaxf(np, 1.0f);
        }
    }
    for (int r = lane2; r < T; r += 64) V += (vmask[r] != 0) ? 1 : 0;
    double ss2 = 0.0;
    for (int d = lane2; d < D; d += 64) { double v = (double)svec[d]; ss2 += v * v; }
#pragma unroll
    for (int off = 32; off > 0; off >>= 1) {
        cl += __shfl_xor(cl, off);
        sp += __shfl_xor(sp, off);
        dv += __shfl_xor(dv, off);
        nval += __shfl_xor(nval, off);
        ndv += __shfl_xor(ndv, off);
        V += __shfl_xor(V, off);
        ss2 += __shfl_xor(ss2, off);
    }
    if (lane2 == 0) {
        int nv = nval > 1 ? nval : 1;
        int nd = ndv > 1 ? ndv : 1;
        float cluster = cl / (float)nv * CLST_SCALE;
        float sep = sp / (float)nv * SEP_SCALE;
        float div = dv / (float)nd * DIV_SCALE;
        double contra_sum = ss2 - *diag;
        long long nvp = (long long)V * (long long)V - (long long)V;
        if (nvp < 1) nvp = 1;
        float contrastive = (float)(contra_sum / (double)nvp) * CONTRASTIVE_SCALE;
        out[0] = cluster;
        out[1] = sep;
        out[2] = div;
        out[3] = contrastive;
        out[4] = cluster + sep + div + contrastive;
    }
}

extern "C" void kernel_launch(void* const* d_in, const int* in_sizes, int n_in,
                              void* d_out, int out_size, void* d_ws, size_t ws_size,
                              hipStream_t stream) {
    const float* sims = (const float*)d_in[0];
    const int* labels = (const int*)d_in[1];
    const float* protos = (const float*)d_in[2];
    const int* pidx = (const int*)d_in[3];
    const int* vmask = (const int*)d_in[4];
    float* out = (float*)d_out;

    int B = in_sizes[1];
    int C = in_sizes[3] / 2;
    int T = in_sizes[4];
    int D = in_sizes[2] / T;
    int P = in_sizes[0] / (B * C);

    char* ws = (char*)d_ws;
    double* diag = (double*)ws;
    unsigned* done = (unsigned*)(ws + 8);
    float* cls3 = (float*)(ws + 16);
    float* cls_pair = cls3 + 3 * C;
    float* svec = cls_pair + C;
    float* own_arr = svec + D;
    float* sep_arr = own_arr + B;

    int rowlen = C * P;
    int strideF = ((rowlen + 3) & ~3) + 8;
    int rowsPB = 65536 / (strideF * 4);
    if (rowsPB > 16) rowsPB = 16;
    if (rowsPB < 1) rowsPB = 1;
    int blkA = rowsPB * 64;
    int nbA = (B + rowsPB - 1) / rowsPB;
    size_t shmA = (size_t)rowsPB * strideF * sizeof(float);
    front_kernel<<<dim3(nbA), dim3(blkA), shmA, stream>>>(
        sims, labels, pidx, own_arr, sep_arr, cls3, svec, diag, done,
        B, C, D, P, strideF);

    int nSeg = (B + 255) / 256;
    int rpb = (T + NVEC - 1) / NVEC;
    int chunk = 57344 / (D * 4);
    if (chunk < 1) chunk = 1;
    if (chunk > rpb) chunk = rpb;
    if (chunk > 128) chunk = 128;
    int gramRows = (P < 128) ? P : 128;
    int ldsF = 3 * C;
    if (gramRows * D > ldsF) ldsF = gramRows * D;
    if (chunk * D > ldsF) ldsF = chunk * D;
    size_t shmB = (size_t)ldsF * sizeof(float);
    unsigned nbTot = (unsigned)(nSeg + C + NVEC);

    // TIMING PROBE: reduce 3x (output-correct, see kernel comment).
    for (int rep = 0; rep < 3; ++rep) {
        reduce_kernel<<<dim3(nbTot), dim3(256), shmB, stream>>>(
            labels, own_arr, sep_arr, pidx, vmask, protos,
            cls3, cls_pair, svec, diag, done, out,
            B, C, T, D, P, nSeg, rpb, chunk, nbTot);
    }
}

// Round 11
// 144.353 us; speedup vs baseline: 1.1427x; 1.1427x over previous
//
#include <hip/hip_runtime.h>
#include <hip/hip_bf16.h>
#include <math.h>

#define MARGIN_C 0.3f
#define CLST_SCALE 0.8f
#define SEP_SCALE 0.08f
#define DIV_SCALE 0.01f
#define CONTRASTIVE_SCALE 0.1f

#define INFF __builtin_huge_valf()
#define NHIST 16
#define NVSUM 16

// ---------------- K_A: per-sample min-distance, wave-per-sample ------------
// Measured (R8 probe): F ~= 15 us, ~4.4 TB/s effective on the 65.5 MB read.
// Three structural rewrites (R2/R6/R7) converged here; treated as at-ceiling.
extern __shared__ float fk_lds[];
__global__ __launch_bounds__(1024) void front_kernel(
    const float* __restrict__ sims, const int* __restrict__ labels,
    const int* __restrict__ pidx,
    float* __restrict__ own_arr, float* __restrict__ sep_arr,
    float* __restrict__ cls3, float* __restrict__ svec,
    unsigned* __restrict__ done, int B, int C, int D, int P, int strideF) {
    int t = threadIdx.x;
    int nthr = blockDim.x;
    int wave = t >> 6, lane = t & 63;
    int bid = blockIdx.x;
    if (bid == 0) {
        for (int i = t; i < 3 * C; i += nthr) cls3[i] = 0.0f;
        for (int i = t; i < D; i += nthr) svec[i] = 0.0f;
        if (t == 0) *done = 0u;
    }
    int rowlen = C * P;
    int rows = nthr >> 6;
    int b = bid * rows + wave;
    float* row = fk_lds + wave * strideF;
    if (b < B) {
        const float* src = sims + (size_t)b * rowlen;
        if ((rowlen & 3) == 0) {
            int nf4 = rowlen >> 2;
            const float4* s4 = reinterpret_cast<const float4*>(src);
            for (int q = lane; q < nf4; q += 64)
                *reinterpret_cast<float4*>(row + 4 * q) = s4[q];
        } else {
            for (int q = lane; q < rowlen; q += 64) row[q] = src[q];
        }
    }
    __syncthreads();
    if (b >= B) return;
    int label = labels[b];
    float own = INFF, other = INFF;
    for (int cc = 0; cc < C; cc += 64) {
        int c = cc + lane;
        if (c < C) {
            int cnt = pidx[2 * c + 1] - pidx[2 * c];
            const float* cb = row + c * P;
            float m = INFF;
            if ((P & 1) == 0) {
                for (int p = 0; p < P; p += 2) {
                    float2 v = *reinterpret_cast<const float2*>(cb + p);
                    float d0 = (p < cnt) ? (1.0f - v.x) : INFF;
                    float d1 = (p + 1 < cnt) ? (1.0f - v.y) : INFF;
                    m = fminf(m, fminf(d0, d1));
                }
            } else {
                for (int p = 0; p < P; ++p) {
                    float v = cb[p];
                    m = fminf(m, (p < cnt) ? (1.0f - v) : INFF);
                }
            }
            if (c == label) own = m;
            else other = fminf(other, m);
        }
    }
#pragma unroll
    for (int off = 32; off > 0; off >>= 1) {
        own = fminf(own, __shfl_xor(own, off));
        other = fminf(other, __shfl_xor(other, off));
    }
    if (lane == 0) {
        own_arr[b] = own;
        sep_arr[b] = fmaxf(MARGIN_C - other, 0.0f);
    }
}

// ---------------- K_B: {hist | wave-class Gram | wave-row vecsum} + final --
// Latency-minimized rebuild of R7's reduce (measured ~16 us via R10 probe):
//  - gram: lane = pair (all 45 pairs + 10 self-dots in parallel per wave)
//  - vecsum: wave-per-row, in-wave shfl norm, no staged-LDS double pass
//  - diag term deleted: ||pn_i||^2 == 1 exactly => diag = V (valid count)
extern __shared__ float rk_lds[];
__global__ __launch_bounds__(256) void mid_kernel(
    const int* __restrict__ labels, const float* __restrict__ own_arr,
    const float* __restrict__ sep_arr, const int* __restrict__ pidx,
    const int* __restrict__ vmask, const float* __restrict__ protos,
    float* __restrict__ cls3, float* __restrict__ cls_pair,
    float* __restrict__ svec, unsigned* __restrict__ done,
    float* __restrict__ out,
    int B, int C, int T, int D, int P, int cpb, int SD,
    int sampPerHist, int nGram, unsigned nbTot) {
    __shared__ float invn_s[4][128];
    __shared__ unsigned lastf;
    int t = threadIdx.x, bid = blockIdx.x;
    int wv = t >> 6, lane = t & 63;

    if (bid < NHIST) {
        // ---- segment histogram: sampPerHist samples, LDS bins ----
        for (int i = t; i < 3 * C; i += 256) rk_lds[i] = 0.0f;
        __syncthreads();
        int i0 = bid * sampPerHist;
        int i1 = i0 + sampPerHist;
        if (i1 > B) i1 = B;
        for (int i = i0 + t; i < i1; i += 256) {
            int lb = labels[i];
            atomicAdd(&rk_lds[lb], own_arr[i]);
            atomicAdd(&rk_lds[C + lb], 1.0f);
            atomicAdd(&rk_lds[2 * C + lb], sep_arr[i]);
        }
        __syncthreads();
        for (int i2 = t; i2 < 3 * C; i2 += 256) {
            float v = rk_lds[i2];
            if (v != 0.0f) unsafeAtomicAdd(&cls3[i2], v);
        }
    } else if (bid < NHIST + nGram) {
        // ---- per-class Gram: one wave per class, lane = pair ----
        int gb = bid - NHIST;
        int c = gb * cpb + wv;
        bool active = (wv < cpb) && (c < C);
        int s0 = 0, n = 0;
        float* my = rk_lds + wv * P * SD;
        if (active) {
            s0 = pidx[2 * c];
            int e = pidx[2 * c + 1];
            n = e - s0;
            if (n < 0) n = 0;
            if (n > P) n = P;
            if (n > 128) n = 128;
            // stage class rows (contiguous in protos) into LDS, stride SD
            if ((D & 3) == 0) {
                int nf4 = (n * D) >> 2;
                const float4* src = reinterpret_cast<const float4*>(protos + (size_t)s0 * D);
                for (int g = lane; g < nf4; g += 64) {
                    float4 v = src[g];
                    int gi = g * 4;
                    int i = (int)((unsigned)gi / (unsigned)D);
                    int q = gi - i * D;
                    *reinterpret_cast<float4*>(my + i * SD + q) = v;
                }
            } else {
                for (int g = lane; g < n * D; g += 64) {
                    int i = (int)((unsigned)g / (unsigned)D);
                    int q = g - i * D;
                    my[i * SD + q] = protos[(size_t)s0 * D + g];
                }
            }
        }
        __syncthreads();
        if (active) {
            // self-dots -> invn (lanes 0..n-1 in parallel)
            for (int i = lane; i < n; i += 64) {
                float ss = 0.0f;
                for (int q = 0; q < D; ++q) { float v = my[i * SD + q]; ss += v * v; }
                invn_s[wv][i] = 1.0f / fmaxf(sqrtf(ss), 1e-12f);
            }
        }
        __syncthreads();
        float tot = 0.0f;
        if (active) {
            int npair = n * (n - 1) / 2;
            for (int p = lane; p < npair; p += 64) {
                int i = 0, rem = p;
                while (rem >= n - 1 - i) { rem -= n - 1 - i; ++i; }
                int j = i + 1 + rem;
                float acc = 0.0f;
                for (int q = 0; q < D; ++q) acc += my[i * SD + q] * my[j * SD + q];
                tot += 2.0f * fmaxf(acc * invn_s[wv][i] * invn_s[wv][j] - 0.5f, 0.0f);
            }
#pragma unroll
            for (int off = 32; off > 0; off >>= 1) tot += __shfl_xor(tot, off);
            if (lane == 0) cls_pair[c] = tot;
        }
        __syncthreads();
    } else {
        // ---- vecsum: wave-per-row, in-wave norm, LDS-accumulated ----
        int vb = bid - NHIST - nGram;
        for (int i = t; i < D; i += 256) rk_lds[i] = 0.0f;
        __syncthreads();
        int gw = vb * 4 + wv;                 // 0 .. NVSUM*4-1
        int nw = NVSUM * 4;
        if ((D & 3) == 0 && D <= 1024) {
            int nf4 = D >> 2;                 // lane covers nf4<=256 via stride
            for (int r = gw; r < T; r += nw) {
                if (vmask[r] == 0) continue;
                const float4* rp = reinterpret_cast<const float4*>(protos + (size_t)r * D);
                float4 v0 = make_float4(0.f, 0.f, 0.f, 0.f);
                float ss = 0.0f;
                // up to 4 chunks of 64 lanes each; D=256 -> exactly 1
                for (int k = lane; k < nf4; k += 64) {
                    float4 v = rp[k];
                    ss += v.x * v.x + v.y * v.y + v.z * v.z + v.w * v.w;
                }
#pragma unroll
                for (int off = 32; off > 0; off >>= 1) ss += __shfl_xor(ss, off);
                float inv = 1.0f / fmaxf(sqrtf(ss), 1e-12f);
                for (int k = lane; k < nf4; k += 64) {
                    float4 v = rp[k];
                    atomicAdd(&rk_lds[4 * k + 0], v.x * inv);
                    atomicAdd(&rk_lds[4 * k + 1], v.y * inv);
                    atomicAdd(&rk_lds[4 * k + 2], v.z * inv);
                    atomicAdd(&rk_lds[4 * k + 3], v.w * inv);
                }
                (void)v0;
            }
        } else {
            for (int r = gw; r < T; r += nw) {
                if (vmask[r] == 0) continue;
                const float* rp = protos + (size_t)r * D;
                float ss = 0.0f;
                for (int k = lane; k < D; k += 64) { float v = rp[k]; ss += v * v; }
#pragma unroll
                for (int off = 32; off > 0; off >>= 1) ss += __shfl_xor(ss, off);
                float inv = 1.0f / fmaxf(sqrtf(ss), 1e-12f);
                for (int k = lane; k < D; k += 64) atomicAdd(&rk_lds[k], rp[k] * inv);
            }
        }
        __syncthreads();
        for (int d = t; d < D; d += 256) {
            float v = rk_lds[d];
            if (v != 0.0f) unsafeAtomicAdd(&svec[d], v);
        }
    }

    // ---- fused finalize: last block combines everything ----
    __threadfence();
    if (t == 0) lastf = (atomicAdd(done, 1u) == nbTot - 1u) ? 1u : 0u;
    __syncthreads();
    if (!lastf || t >= 64) return;
    __threadfence();  // acquire
    int lane2 = t;
    float cl = 0.0f, sp = 0.0f, dv = 0.0f;
    int nval = 0, ndv = 0, V = 0;
    const float* cls_sum = cls3;
    const float* cls_n = cls3 + C;
    const float* sep_sum = cls3 + 2 * C;
    for (int c = lane2; c < C; c += 64) {
        float n = cls_n[c];
        if (n > 0.0f) {
            nval += 1;
            float nm = fmaxf(n, 1.0f);
            float w = 1.0f / sqrtf(n + 1e-6f);
            cl += w * (cls_sum[c] / nm);
            sp += sep_sum[c] / nm;
        }
        int cnt = pidx[2 * c + 1] - pidx[2 * c];
        if (cnt > 1) {
            ndv += 1;
            float np = (float)(cnt * (cnt - 1));
            dv += cls_pair[c] / fmaxf(np, 1.0f);
        }
    }
    for (int r = lane2; r < T; r += 64) V += (vmask[r] != 0) ? 1 : 0;
    double ss2 = 0.0;
    for (int d = lane2; d < D; d += 64) { double v = (double)svec[d]; ss2 += v * v; }
#pragma unroll
    for (int off = 32; off > 0; off >>= 1) {
        cl += __shfl_xor(cl, off);
        sp += __shfl_xor(sp, off);
        dv += __shfl_xor(dv, off);
        nval += __shfl_xor(nval, off);
        ndv += __shfl_xor(ndv, off);
        V += __shfl_xor(V, off);
        ss2 += __shfl_xor(ss2, off);
    }
    if (lane2 == 0) {
        int nv = nval > 1 ? nval : 1;
        int nd = ndv > 1 ? ndv : 1;
        float cluster = cl / (float)nv * CLST_SCALE;
        float sep = sp / (float)nv * SEP_SCALE;
        float div = dv / (float)nd * DIV_SCALE;
        // ||pn_i||^2 == 1 for every valid row => diagonal sum == V
        double contra_sum = ss2 - (double)V;
        long long nvp = (long long)V * (long long)V - (long long)V;
        if (nvp < 1) nvp = 1;
        float contrastive = (float)(contra_sum / (double)nvp) * CONTRASTIVE_SCALE;
        out[0] = cluster;
        out[1] = sep;
        out[2] = div;
        out[3] = contrastive;
        out[4] = cluster + sep + div + contrastive;
    }
}

extern "C" void kernel_launch(void* const* d_in, const int* in_sizes, int n_in,
                              void* d_out, int out_size, void* d_ws, size_t ws_size,
                              hipStream_t stream) {
    const float* sims = (const float*)d_in[0];
    const int* labels = (const int*)d_in[1];
    const float* protos = (const float*)d_in[2];
    const int* pidx = (const int*)d_in[3];
    const int* vmask = (const int*)d_in[4];
    float* out = (float*)d_out;

    int B = in_sizes[1];
    int C = in_sizes[3] / 2;
    int T = in_sizes[4];
    int D = in_sizes[2] / T;
    int P = in_sizes[0] / (B * C);

    // ws: done u32 [8,12); floats from 16: cls3[3C], cls_pair[C], svec[D],
    // own[B], sep[B].
    char* ws = (char*)d_ws;
    unsigned* done = (unsigned*)(ws + 8);
    float* cls3 = (float*)(ws + 16);
    float* cls_pair = cls3 + 3 * C;
    float* svec = cls_pair + C;
    float* own_arr = svec + D;
    float* sep_arr = own_arr + B;

    // K_A: wave-per-sample front
    int rowlen = C * P;
    int strideF = ((rowlen + 3) & ~3) + 8;
    int rowsPB = 65536 / (strideF * 4);
    if (rowsPB > 16) rowsPB = 16;
    if (rowsPB < 1) rowsPB = 1;
    int blkA = rowsPB * 64;
    int nbA = (B + rowsPB - 1) / rowsPB;
    size_t shmA = (size_t)rowsPB * strideF * sizeof(float);
    front_kernel<<<dim3(nbA), dim3(blkA), shmA, stream>>>(
        sims, labels, pidx, own_arr, sep_arr, cls3, svec, done,
        B, C, D, P, strideF);

    // K_B: mid + finalize
    int Pc = (P < 128) ? P : 128;
    int SD = ((D + 3) & ~3) + 4;            // float4-aligned + bank skew
    int cpb = 4;
    while (cpb > 1 && cpb * Pc * SD * 4 > 60000) cpb >>= 1;
    int nGram = (C + cpb - 1) / cpb;
    int sampPerHist = (B + NHIST - 1) / NHIST;
    int ldsF = 3 * C;
    if (cpb * Pc * SD > ldsF) ldsF = cpb * Pc * SD;
    if (D > ldsF) ldsF = D;
    size_t shmB = (size_t)ldsF * sizeof(float);
    unsigned nbTot = (unsigned)(NHIST + nGram + NVSUM);
    mid_kernel<<<dim3(nbTot), dim3(256), shmB, stream>>>(
        labels, own_arr, sep_arr, pidx, vmask, protos,
        cls3, cls_pair, svec, done, out,
        B, C, T, D, Pc, cpb, SD, sampPerHist, nGram, nbTot);
}